// Round 1
// baseline (1528.128 us; speedup 1.0000x reference)
//
#include <hip/hip_runtime.h>

typedef _Float16 f16x8 __attribute__((ext_vector_type(8)));
typedef float f32x4 __attribute__((ext_vector_type(4)));

#define N_PIX 4096
#define C_IN  512
#define BN_INV 0.99999500003749969f  // 1/sqrt(1+1e-5)

__device__ __forceinline__ f32x4 mfma16(f16x8 a, f16x8 b, f32x4 c) {
  return __builtin_amdgcn_mfma_f32_16x16x32_f16(a, b, c, 0, 0, 0);
}
// NT fragment load: row = base_row + (lane&15), 8 contiguous k at k0 + (lane>>4)*8
__device__ __forceinline__ f16x8 ldnt(const _Float16* base, int row, int ld, int k0, int lane) {
  return *(const f16x8*)(base + (size_t)(row + (lane & 15)) * ld + k0 + ((lane >> 4) << 3));
}

// ---------- x NCHW fp32 -> xT [b][pix][c] fp16 (LDS tile transpose) ----------
__global__ __launch_bounds__(256) void k_xT(const float* __restrict__ x, _Float16* __restrict__ xT) {
  __shared__ float t[32][33];
  int b = blockIdx.z, p0 = blockIdx.x * 32, c0 = blockIdx.y * 32;
  int tx = threadIdx.x & 31, ty = threadIdx.x >> 5;  // 32 x 8
  const float* xb = x + ((size_t)b * C_IN + c0) * N_PIX + p0;
  for (int i = 0; i < 32; i += 8) t[ty + i][tx] = xb[(size_t)(ty + i) * N_PIX + tx];
  __syncthreads();
  _Float16* o = xT + ((size_t)b * N_PIX + p0) * C_IN + c0;
  for (int i = 0; i < 32; i += 8) o[(size_t)(ty + i) * C_IN + tx] = (_Float16)t[tx][ty + i];
}

// ---------- generic fp32 -> fp16 ----------
__global__ __launch_bounds__(256) void k_f2h(const float* __restrict__ in, _Float16* __restrict__ out, int n) {
  int i = blockIdx.x * 256 + threadIdx.x;
  if (i < n) out[i] = (_Float16)in[i];
}

// ---------- pack 3x3 dilated conv weights: [conv][tap][oc][c] fp16 ----------
__global__ __launch_bounds__(256) void k_packw(const float* __restrict__ w2, const float* __restrict__ w3,
                                               const float* __restrict__ w4, _Float16* __restrict__ wp) {
  int idx = blockIdx.x * 256 + threadIdx.x;  // 3*9*128*512 = 1769472
  int conv = idx / 589824;
  int t1 = idx % 589824;
  int tap = t1 / 65536;
  int t2 = t1 % 65536;
  int oc = t2 / 512, c = t2 % 512;
  const float* w = (conv == 0) ? w2 : (conv == 1) ? w3 : w4;
  wp[idx] = (_Float16)w[(size_t)(oc * 512 + c) * 9 + tap];
}

// ---------- per (b,c) mean over pixels ----------
__global__ __launch_bounds__(256) void k_mean(const float* __restrict__ x, float* __restrict__ meanv) {
  int c = blockIdx.x, b = blockIdx.y;
  const float* p = x + ((size_t)b * C_IN + c) * N_PIX;
  float s = 0.f;
  for (int i = threadIdx.x; i < N_PIX; i += 256) s += p[i];
  for (int off = 32; off; off >>= 1) s += __shfl_down(s, off);
  __shared__ float ls[4];
  if ((threadIdx.x & 63) == 0) ls[threadIdx.x >> 6] = s;
  __syncthreads();
  if (threadIdx.x == 0) meanv[(size_t)b * C_IN + c] = (ls[0] + ls[1] + ls[2] + ls[3]) * (1.f / N_PIX);
}

// ---------- branch 5: 1x1 conv on pooled vector + BN + ReLU ----------
__global__ void k_p5(const float* __restrict__ w5, const float* __restrict__ meanv,
                     const float* __restrict__ bnS, const float* __restrict__ bnB, _Float16* __restrict__ p5h) {
  int b = blockIdx.x, oc = threadIdx.x;  // 128 threads
  const float* m = meanv + (size_t)b * C_IN;
  const float* w = w5 + (size_t)oc * C_IN;
  float s = 0.f;
  for (int c = 0; c < C_IN; ++c) s += w[c] * m[c];
  float v = fmaxf(s * bnS[oc] * BN_INV + bnB[oc], 0.f);
  p5h[b * 128 + oc] = (_Float16)v;
}

// ---------- broadcast b5 into featT channels [512,640) ----------
__global__ __launch_bounds__(256) void k_b5(const _Float16* __restrict__ p5h, _Float16* __restrict__ featT) {
  int i = blockIdx.x * 256 + threadIdx.x;  // 4*4096*128
  int oc = i & 127, p = (i >> 7) & 4095, b = i >> 19;
  featT[((size_t)b * N_PIX + p) * 640 + 512 + oc] = p5h[b * 128 + oc];
}

// ---------- b1: 1x1 conv 512->128 + BN + ReLU -> featT[:, 0:128) ----------
__global__ __launch_bounds__(256) void k_conv1(const _Float16* __restrict__ xT, const _Float16* __restrict__ w1h,
                                               const float* __restrict__ bnS, const float* __restrict__ bnB,
                                               _Float16* __restrict__ featT) {
  int b = blockIdx.y, p0 = blockIdx.x * 64;
  int tid = threadIdx.x, wid = tid >> 6, lane = tid & 63;
  const _Float16* A = xT + (size_t)b * N_PIX * C_IN;
  int pr = p0 + wid * 16;
  f32x4 acc[8] = {};
  for (int kk = 0; kk < 16; ++kk) {
    f16x8 af = ldnt(A, pr, C_IN, kk * 32, lane);
#pragma unroll
    for (int nn = 0; nn < 8; ++nn) {
      f16x8 bf = ldnt(w1h, nn * 16, C_IN, kk * 32, lane);
      acc[nn] = mfma16(af, bf, acc[nn]);
    }
  }
  _Float16* F = featT + (size_t)b * N_PIX * 640;
#pragma unroll
  for (int nn = 0; nn < 8; ++nn) {
    int oc = nn * 16 + (lane & 15);
    float inv = bnS[oc] * BN_INV, bs = bnB[oc];
#pragma unroll
    for (int r = 0; r < 4; ++r) {
      int pix = pr + ((lane >> 4) << 2) + r;
      F[(size_t)pix * 640 + oc] = (_Float16)fmaxf(acc[nn][r] * inv + bs, 0.f);
    }
  }
}

// ---------- b2..b4: dilated 3x3 conv (implicit GEMM, 9 masked taps) ----------
__global__ __launch_bounds__(256) void k_conv3(const _Float16* __restrict__ xT, const _Float16* __restrict__ wp,
                                               int dil, const float* __restrict__ bnS, const float* __restrict__ bnB,
                                               _Float16* __restrict__ featT, int brOff) {
  int b = blockIdx.y, p0 = blockIdx.x * 64;
  int tid = threadIdx.x, wid = tid >> 6, lane = tid & 63;
  const _Float16* A = xT + (size_t)b * N_PIX * C_IN;
  int pr = p0 + wid * 16;
  int p = pr + (lane & 15);
  int y = p >> 6, xx = p & 63;
  f32x4 acc[8] = {};
  for (int tap = 0; tap < 9; ++tap) {
    int dy = (tap / 3 - 1) * dil, dx = (tap % 3 - 1) * dil;
    int py = y + dy, px = xx + dx;
    bool valid = ((unsigned)py < 64u) && ((unsigned)px < 64u);
    const _Float16* wt = wp + (size_t)tap * 128 * C_IN;
    for (int kk = 0; kk < 16; ++kk) {
      f16x8 af = {};
      if (valid) af = *(const f16x8*)(A + (size_t)(p + dy * 64 + dx) * C_IN + ((lane >> 4) << 3) + kk * 32);
#pragma unroll
      for (int nn = 0; nn < 8; ++nn) {
        f16x8 bf = ldnt(wt, nn * 16, C_IN, kk * 32, lane);
        acc[nn] = mfma16(af, bf, acc[nn]);
      }
    }
  }
  _Float16* F = featT + (size_t)b * N_PIX * 640;
#pragma unroll
  for (int nn = 0; nn < 8; ++nn) {
    int oc = nn * 16 + (lane & 15);
    float inv = bnS[oc] * BN_INV, bs = bnB[oc];
#pragma unroll
    for (int r = 0; r < 4; ++r) {
      int pix = pr + ((lane >> 4) << 2) + r;
      F[(size_t)pix * 640 + brOff + oc] = (_Float16)fmaxf(acc[nn][r] * inv + bs, 0.f);
    }
  }
}

// ---------- q/k: 1x1 conv 640->128 + bias -> [b][pix][128] fp16 ----------
__global__ __launch_bounds__(256) void k_qk(const _Float16* __restrict__ featT, const _Float16* __restrict__ wh,
                                            const float* __restrict__ bias, _Float16* __restrict__ oT) {
  int b = blockIdx.y, p0 = blockIdx.x * 64;
  int tid = threadIdx.x, wid = tid >> 6, lane = tid & 63;
  const _Float16* A = featT + (size_t)b * N_PIX * 640;
  int pr = p0 + wid * 16;
  f32x4 acc[8] = {};
  for (int kk = 0; kk < 20; ++kk) {
    f16x8 af = ldnt(A, pr, 640, kk * 32, lane);
#pragma unroll
    for (int nn = 0; nn < 8; ++nn) {
      f16x8 bf = ldnt(wh, nn * 16, 640, kk * 32, lane);
      acc[nn] = mfma16(af, bf, acc[nn]);
    }
  }
  _Float16* O = oT + (size_t)b * N_PIX * 128;
#pragma unroll
  for (int nn = 0; nn < 8; ++nn) {
    int oc = nn * 16 + (lane & 15);
    float bb = bias[oc];
#pragma unroll
    for (int r = 0; r < 4; ++r) {
      int pix = pr + ((lane >> 4) << 2) + r;
      O[(size_t)pix * 128 + oc] = (_Float16)(acc[nn][r] + bb);
    }
  }
}

// ---------- v: 1x1 conv 512->512 + bias -> [b][c][pix] fp16 (channel-major) ----------
__global__ __launch_bounds__(256) void k_v(const _Float16* __restrict__ xT, const _Float16* __restrict__ wvh,
                                           const float* __restrict__ bv, _Float16* __restrict__ vv) {
  int b = blockIdx.z, oc0 = blockIdx.x * 64, p0 = blockIdx.y * 128;
  int tid = threadIdx.x, wid = tid >> 6, lane = tid & 63;
  const _Float16* Bm = xT + (size_t)b * N_PIX * C_IN;
  int or0 = oc0 + wid * 16;
  f32x4 acc[8] = {};
  for (int kk = 0; kk < 16; ++kk) {
    f16x8 af = ldnt(wvh, or0, C_IN, kk * 32, lane);
#pragma unroll
    for (int nn = 0; nn < 8; ++nn) {
      f16x8 bf = ldnt(Bm, p0 + nn * 16, C_IN, kk * 32, lane);
      acc[nn] = mfma16(af, bf, acc[nn]);
    }
  }
  _Float16* V = vv + (size_t)b * C_IN * N_PIX;
#pragma unroll
  for (int r = 0; r < 4; ++r) {
    int oc = or0 + ((lane >> 4) << 2) + r;
    float bb = bv[oc];
#pragma unroll
    for (int nn = 0; nn < 8; ++nn) {
      int pix = p0 + nn * 16 + (lane & 15);
      V[(size_t)oc * N_PIX + pix] = (_Float16)(acc[nn][r] + bb);
    }
  }
}

// ---------- pass 1: row max + sumexp of energy (online softmax stats) ----------
__global__ __launch_bounds__(256) void k_pass1(const _Float16* __restrict__ qT, const _Float16* __restrict__ kT,
                                               float* __restrict__ rmax, float* __restrict__ rsum) {
  int b = blockIdx.y, n0 = blockIdx.x * 64;
  int tid = threadIdx.x, wid = tid >> 6, lane = tid & 63;
  const _Float16* Q = qT + (size_t)b * N_PIX * 128;
  const _Float16* K = kT + (size_t)b * N_PIX * 128;
  f16x8 qf[4];
#pragma unroll
  for (int kk = 0; kk < 4; ++kk) qf[kk] = ldnt(Q, n0 + wid * 16, 128, kk * 32, lane);
  float mx[4], sm[4];
#pragma unroll
  for (int r = 0; r < 4; ++r) { mx[r] = -3.4e38f; sm[r] = 0.f; }
  for (int it = 0; it < 64; ++it) {
    int m0 = it * 64;
    f32x4 s[4];
#pragma unroll
    for (int mm = 0; mm < 4; ++mm) {
      f32x4 a = {};
#pragma unroll
      for (int kk = 0; kk < 4; ++kk) {
        f16x8 kf = ldnt(K, m0 + mm * 16, 128, kk * 32, lane);
        a = mfma16(qf[kk], kf, a);
      }
      s[mm] = a;
    }
#pragma unroll
    for (int r = 0; r < 4; ++r) {
      float vmax = fmaxf(fmaxf(s[0][r], s[1][r]), fmaxf(s[2][r], s[3][r]));
      float newm = fmaxf(mx[r], vmax);
      sm[r] = sm[r] * __expf(mx[r] - newm) +
              __expf(s[0][r] - newm) + __expf(s[1][r] - newm) +
              __expf(s[2][r] - newm) + __expf(s[3][r] - newm);
      mx[r] = newm;
    }
  }
#pragma unroll
  for (int r = 0; r < 4; ++r) {
    float m = mx[r], l = sm[r];
#pragma unroll
    for (int off = 1; off < 16; off <<= 1) {
      float mo = __shfl_xor(m, off);
      float lo = __shfl_xor(l, off);
      float mn = fmaxf(m, mo);
      l = l * __expf(m - mn) + lo * __expf(mo - mn);
      m = mn;
    }
    if ((lane & 15) == 0) {
      int row = n0 + wid * 16 + ((lane >> 4) << 2) + r;
      rmax[(size_t)b * N_PIX + row] = m;
      rsum[(size_t)b * N_PIX + row] = l;
    }
  }
}

// ---------- pass 2: fused S recompute -> P -> PV -> y = x + gamma*O/sum ----------
__global__ __launch_bounds__(256) void k_pass2(const _Float16* __restrict__ qT, const _Float16* __restrict__ kT,
                                               const _Float16* __restrict__ vv, const float* __restrict__ rmax,
                                               const float* __restrict__ rsum, const float* __restrict__ x,
                                               const float* __restrict__ gamma, float* __restrict__ out) {
  __shared__ _Float16 P[64 * 72];  // 72-half stride: 16B-aligned rows, 2-way banks max
  int b = blockIdx.z, n0 = blockIdx.x * 64, c0 = blockIdx.y * 128;
  int tid = threadIdx.x, wid = tid >> 6, lane = tid & 63;
  const _Float16* Q = qT + (size_t)b * N_PIX * 128;
  const _Float16* K = kT + (size_t)b * N_PIX * 128;
  const _Float16* V = vv + (size_t)b * C_IN * N_PIX;
  float g = gamma[0];
  f16x8 qf[4];
#pragma unroll
  for (int kk = 0; kk < 4; ++kk) qf[kk] = ldnt(Q, n0 + wid * 16, 128, kk * 32, lane);
  float pmax[4];
#pragma unroll
  for (int r = 0; r < 4; ++r) {
    int row = n0 + wid * 16 + ((lane >> 4) << 2) + r;
    pmax[r] = rmax[(size_t)b * N_PIX + row];
  }
  f32x4 acc[2][4] = {};
  for (int it = 0; it < 64; ++it) {
    int m0 = it * 64;
    // phase A: S tile (wave's 16 rows x 64 cols), P = exp(S - max) -> LDS
#pragma unroll
    for (int mm = 0; mm < 4; ++mm) {
      f32x4 s = {};
#pragma unroll
      for (int kk = 0; kk < 4; ++kk) {
        f16x8 kf = ldnt(K, m0 + mm * 16, 128, kk * 32, lane);
        s = mfma16(qf[kk], kf, s);
      }
#pragma unroll
      for (int r = 0; r < 4; ++r) {
        float pv = __expf(s[r] - pmax[r]);
        P[(wid * 16 + ((lane >> 4) << 2) + r) * 72 + mm * 16 + (lane & 15)] = (_Float16)pv;
      }
    }
    __syncthreads();
    // phase B: O'[c][n] += V[c][m] * P[n][m]^T  (wave owns 32 c-rows x 64 n)
#pragma unroll
    for (int k2 = 0; k2 < 2; ++k2) {
      f16x8 pb[4];
#pragma unroll
      for (int nn = 0; nn < 4; ++nn)
        pb[nn] = *(const f16x8*)(P + (size_t)(nn * 16 + (lane & 15)) * 72 + k2 * 32 + ((lane >> 4) << 3));
#pragma unroll
      for (int cc = 0; cc < 2; ++cc) {
        f16x8 af = ldnt(V, c0 + wid * 32 + cc * 16, N_PIX, m0 + k2 * 32, lane);
#pragma unroll
        for (int nn = 0; nn < 4; ++nn) acc[cc][nn] = mfma16(af, pb[nn], acc[cc][nn]);
      }
    }
    __syncthreads();
  }
  // epilogue: normalize by row sum, y = x + g*O
  float inv_s[4];
#pragma unroll
  for (int nn = 0; nn < 4; ++nn) {
    int pix = n0 + nn * 16 + (lane & 15);
    inv_s[nn] = 1.f / rsum[(size_t)b * N_PIX + pix];
  }
#pragma unroll
  for (int cc = 0; cc < 2; ++cc) {
#pragma unroll
    for (int r = 0; r < 4; ++r) {
      int oc = c0 + wid * 32 + cc * 16 + ((lane >> 4) << 2) + r;
#pragma unroll
      for (int nn = 0; nn < 4; ++nn) {
        int pix = n0 + nn * 16 + (lane & 15);
        size_t idx = ((size_t)(b * C_IN + oc)) * N_PIX + pix;
        out[idx] = fmaf(g * inv_s[nn], acc[cc][nn][r], x[idx]);
      }
    }
  }
}

extern "C" void kernel_launch(void* const* d_in, const int* in_sizes, int n_in,
                              void* d_out, int out_size, void* d_ws, size_t ws_size,
                              hipStream_t stream) {
  const float* x = (const float*)d_in[0];
  const float* wa1 = (const float*)d_in[1];
  const float* wa2 = (const float*)d_in[2];
  const float* wa3 = (const float*)d_in[3];
  const float* wa4 = (const float*)d_in[4];
  const float* wa5 = (const float*)d_in[5];
  const float* bnS = (const float*)d_in[6];
  const float* bnB = (const float*)d_in[7];
  const float* wq = (const float*)d_in[8];
  const float* bq = (const float*)d_in[9];
  const float* wk = (const float*)d_in[10];
  const float* bk = (const float*)d_in[11];
  const float* wv = (const float*)d_in[12];
  const float* bv = (const float*)d_in[13];
  const float* gamma = (const float*)d_in[14];

  char* ws = (char*)d_ws;
  size_t off = 0;
  auto alloc = [&](size_t bytes) -> char* {
    char* p = ws + off;
    off = (off + bytes + 255) & ~(size_t)255;
    return p;
  };
  _Float16* xT = (_Float16*)alloc((size_t)4 * 4096 * 512 * 2);
  _Float16* featT = (_Float16*)alloc((size_t)4 * 4096 * 640 * 2);
  _Float16* qT = (_Float16*)alloc((size_t)4 * 4096 * 128 * 2);
  _Float16* kT = (_Float16*)alloc((size_t)4 * 4096 * 128 * 2);
  _Float16* vvp = (_Float16*)alloc((size_t)4 * 512 * 4096 * 2);
  _Float16* w1h = (_Float16*)alloc((size_t)128 * 512 * 2);
  _Float16* wph = (_Float16*)alloc((size_t)3 * 9 * 128 * 512 * 2);
  _Float16* wqh = (_Float16*)alloc((size_t)128 * 640 * 2);
  _Float16* wkh = (_Float16*)alloc((size_t)128 * 640 * 2);
  _Float16* wvh = (_Float16*)alloc((size_t)512 * 512 * 2);
  float* meanv = (float*)alloc((size_t)4 * 512 * 4);
  _Float16* p5h = (_Float16*)alloc((size_t)4 * 128 * 2);
  float* rmax = (float*)alloc((size_t)4 * 4096 * 4);
  float* rsum = (float*)alloc((size_t)4 * 4096 * 4);
  if (off > ws_size) return;  // workspace too small -> fail loudly via wrong output

  float* out = (float*)d_out;

  // stage inputs
  hipLaunchKernelGGL(k_xT, dim3(128, 16, 4), dim3(256), 0, stream, x, xT);
  hipLaunchKernelGGL(k_f2h, dim3(256), dim3(256), 0, stream, wa1, w1h, 65536);
  hipLaunchKernelGGL(k_f2h, dim3(320), dim3(256), 0, stream, wq, wqh, 81920);
  hipLaunchKernelGGL(k_f2h, dim3(320), dim3(256), 0, stream, wk, wkh, 81920);
  hipLaunchKernelGGL(k_f2h, dim3(1024), dim3(256), 0, stream, wv, wvh, 262144);
  hipLaunchKernelGGL(k_packw, dim3(6912), dim3(256), 0, stream, wa2, wa3, wa4, wph);
  // ASPP
  hipLaunchKernelGGL(k_mean, dim3(512, 4), dim3(256), 0, stream, x, meanv);
  hipLaunchKernelGGL(k_p5, dim3(4), dim3(128), 0, stream, wa5, meanv, bnS + 4 * 128, bnB + 4 * 128, p5h);
  hipLaunchKernelGGL(k_b5, dim3(8192), dim3(256), 0, stream, p5h, featT);
  hipLaunchKernelGGL(k_conv1, dim3(64, 4), dim3(256), 0, stream, xT, w1h, bnS, bnB, featT);
  hipLaunchKernelGGL(k_conv3, dim3(64, 4), dim3(256), 0, stream, xT, wph + (size_t)0 * 9 * 128 * 512, 2,
                     bnS + 128, bnB + 128, featT, 128);
  hipLaunchKernelGGL(k_conv3, dim3(64, 4), dim3(256), 0, stream, xT, wph + (size_t)1 * 9 * 128 * 512, 3,
                     bnS + 256, bnB + 256, featT, 256);
  hipLaunchKernelGGL(k_conv3, dim3(64, 4), dim3(256), 0, stream, xT, wph + (size_t)2 * 9 * 128 * 512, 6,
                     bnS + 384, bnB + 384, featT, 384);
  // q, k, v
  hipLaunchKernelGGL(k_qk, dim3(64, 4), dim3(256), 0, stream, featT, wqh, bq, qT);
  hipLaunchKernelGGL(k_qk, dim3(64, 4), dim3(256), 0, stream, featT, wkh, bk, kT);
  hipLaunchKernelGGL(k_v, dim3(8, 32, 4), dim3(256), 0, stream, xT, wvh, bv, vvp);
  // attention
  hipLaunchKernelGGL(k_pass1, dim3(64, 4), dim3(256), 0, stream, qT, kT, rmax, rsum);
  hipLaunchKernelGGL(k_pass2, dim3(64, 4, 4), dim3(256), 0, stream, qT, kT, vvp, rmax, rsum, x, gamma, out);
}

// Round 2
// 1199.238 us; speedup vs baseline: 1.2742x; 1.2742x over previous
//
#include <hip/hip_runtime.h>

typedef _Float16 f16x8 __attribute__((ext_vector_type(8)));
typedef _Float16 f16x4 __attribute__((ext_vector_type(4)));
typedef float f32x4 __attribute__((ext_vector_type(4)));

#define N_PIX 4096
#define C_IN  512
#define BN_INV 0.99999500003749969f  // 1/sqrt(1+1e-5)

__device__ __forceinline__ f32x4 mfma16(f16x8 a, f16x8 b, f32x4 c) {
  return __builtin_amdgcn_mfma_f32_16x16x32_f16(a, b, c, 0, 0, 0);
}
// NT fragment load: row = base_row + (lane&15), 8 contiguous k at k0 + (lane>>4)*8
__device__ __forceinline__ f16x8 ldnt(const _Float16* base, int row, int ld, int k0, int lane) {
  return *(const f16x8*)(base + (size_t)(row + (lane & 15)) * ld + k0 + ((lane >> 4) << 3));
}

// ---------- x NCHW fp32 -> xT [b][pix][c] fp16 (LDS tile transpose) ----------
__global__ __launch_bounds__(256) void k_xT(const float* __restrict__ x, _Float16* __restrict__ xT) {
  __shared__ float t[32][33];
  int b = blockIdx.z, p0 = blockIdx.x * 32, c0 = blockIdx.y * 32;
  int tx = threadIdx.x & 31, ty = threadIdx.x >> 5;  // 32 x 8
  const float* xb = x + ((size_t)b * C_IN + c0) * N_PIX + p0;
  for (int i = 0; i < 32; i += 8) t[ty + i][tx] = xb[(size_t)(ty + i) * N_PIX + tx];
  __syncthreads();
  _Float16* o = xT + ((size_t)b * N_PIX + p0) * C_IN + c0;
  for (int i = 0; i < 32; i += 8) o[(size_t)(ty + i) * C_IN + tx] = (_Float16)t[tx][ty + i];
}

// ---------- generic fp32 -> fp16 ----------
__global__ __launch_bounds__(256) void k_f2h(const float* __restrict__ in, _Float16* __restrict__ out, int n) {
  int i = blockIdx.x * 256 + threadIdx.x;
  if (i < n) out[i] = (_Float16)in[i];
}

// ---------- pack 3x3 dilated conv weights: [conv][tap][oc][c] fp16 ----------
__global__ __launch_bounds__(256) void k_packw(const float* __restrict__ w2, const float* __restrict__ w3,
                                               const float* __restrict__ w4, _Float16* __restrict__ wp) {
  int idx = blockIdx.x * 256 + threadIdx.x;  // 3*9*128*512 = 1769472
  int conv = idx / 589824;
  int t1 = idx % 589824;
  int tap = t1 / 65536;
  int t2 = t1 % 65536;
  int oc = t2 / 512, c = t2 % 512;
  const float* w = (conv == 0) ? w2 : (conv == 1) ? w3 : w4;
  wp[idx] = (_Float16)w[(size_t)(oc * 512 + c) * 9 + tap];
}

// ---------- per (b,c) mean over pixels ----------
__global__ __launch_bounds__(256) void k_mean(const float* __restrict__ x, float* __restrict__ meanv) {
  int c = blockIdx.x, b = blockIdx.y;
  const float* p = x + ((size_t)b * C_IN + c) * N_PIX;
  float s = 0.f;
  for (int i = threadIdx.x; i < N_PIX; i += 256) s += p[i];
  for (int off = 32; off; off >>= 1) s += __shfl_down(s, off);
  __shared__ float ls[4];
  if ((threadIdx.x & 63) == 0) ls[threadIdx.x >> 6] = s;
  __syncthreads();
  if (threadIdx.x == 0) meanv[(size_t)b * C_IN + c] = (ls[0] + ls[1] + ls[2] + ls[3]) * (1.f / N_PIX);
}

// ---------- branch 5: 1x1 conv on pooled vector + BN + ReLU ----------
__global__ void k_p5(const float* __restrict__ w5, const float* __restrict__ meanv,
                     const float* __restrict__ bnS, const float* __restrict__ bnB, _Float16* __restrict__ p5h) {
  int b = blockIdx.x, oc = threadIdx.x;  // 128 threads
  const float* m = meanv + (size_t)b * C_IN;
  const float* w = w5 + (size_t)oc * C_IN;
  float s = 0.f;
  for (int c = 0; c < C_IN; ++c) s += w[c] * m[c];
  float v = fmaxf(s * bnS[oc] * BN_INV + bnB[oc], 0.f);
  p5h[b * 128 + oc] = (_Float16)v;
}

// ---------- broadcast b5 into featT channels [512,640) ----------
__global__ __launch_bounds__(256) void k_b5(const _Float16* __restrict__ p5h, _Float16* __restrict__ featT) {
  int i = blockIdx.x * 256 + threadIdx.x;  // 4*4096*128
  int oc = i & 127, p = (i >> 7) & 4095, b = i >> 19;
  featT[((size_t)b * N_PIX + p) * 640 + 512 + oc] = p5h[b * 128 + oc];
}

// ---------- b1: 1x1 conv 512->128 + BN + ReLU -> featT[:, 0:128) ----------
__global__ __launch_bounds__(256) void k_conv1(const _Float16* __restrict__ xT, const _Float16* __restrict__ w1h,
                                               const float* __restrict__ bnS, const float* __restrict__ bnB,
                                               _Float16* __restrict__ featT) {
  int b = blockIdx.y, p0 = blockIdx.x * 64;
  int tid = threadIdx.x, wid = tid >> 6, lane = tid & 63;
  const _Float16* A = xT + (size_t)b * N_PIX * C_IN;
  int pr = p0 + wid * 16;
  f32x4 acc[8] = {};
  for (int kk = 0; kk < 16; ++kk) {
    f16x8 af = ldnt(A, pr, C_IN, kk * 32, lane);
#pragma unroll
    for (int nn = 0; nn < 8; ++nn) {
      f16x8 bf = ldnt(w1h, nn * 16, C_IN, kk * 32, lane);
      acc[nn] = mfma16(af, bf, acc[nn]);
    }
  }
  _Float16* F = featT + (size_t)b * N_PIX * 640;
#pragma unroll
  for (int nn = 0; nn < 8; ++nn) {
    int oc = nn * 16 + (lane & 15);
    float inv = bnS[oc] * BN_INV, bs = bnB[oc];
#pragma unroll
    for (int r = 0; r < 4; ++r) {
      int pix = pr + ((lane >> 4) << 2) + r;
      F[(size_t)pix * 640 + oc] = (_Float16)fmaxf(acc[nn][r] * inv + bs, 0.f);
    }
  }
}

// ---------- b2..b4: dilated 3x3 conv (implicit GEMM, 9 masked taps), oc-split ----------
__global__ __launch_bounds__(256) void k_conv3(const _Float16* __restrict__ xT, const _Float16* __restrict__ wp,
                                               int dil, const float* __restrict__ bnS, const float* __restrict__ bnB,
                                               _Float16* __restrict__ featT, int brOff) {
  int b = blockIdx.z, p0 = blockIdx.x * 64, ocOff = blockIdx.y * 64;
  int tid = threadIdx.x, wid = tid >> 6, lane = tid & 63;
  const _Float16* A = xT + (size_t)b * N_PIX * C_IN;
  int pr = p0 + wid * 16;
  int p = pr + (lane & 15);
  int y = p >> 6, xx = p & 63;
  f32x4 acc[4] = {};
  for (int tap = 0; tap < 9; ++tap) {
    int dy = (tap / 3 - 1) * dil, dx = (tap % 3 - 1) * dil;
    int py = y + dy, px = xx + dx;
    bool valid = ((unsigned)py < 64u) && ((unsigned)px < 64u);
    const _Float16* wt = wp + (size_t)tap * 128 * C_IN;
    for (int kk = 0; kk < 16; ++kk) {
      f16x8 af = {};
      if (valid) af = *(const f16x8*)(A + (size_t)(p + dy * 64 + dx) * C_IN + ((lane >> 4) << 3) + kk * 32);
#pragma unroll
      for (int nn = 0; nn < 4; ++nn) {
        f16x8 bf = ldnt(wt, ocOff + nn * 16, C_IN, kk * 32, lane);
        acc[nn] = mfma16(af, bf, acc[nn]);
      }
    }
  }
  _Float16* F = featT + (size_t)b * N_PIX * 640;
#pragma unroll
  for (int nn = 0; nn < 4; ++nn) {
    int oc = ocOff + nn * 16 + (lane & 15);
    float inv = bnS[oc] * BN_INV, bs = bnB[oc];
#pragma unroll
    for (int r = 0; r < 4; ++r) {
      int pix = pr + ((lane >> 4) << 2) + r;
      F[(size_t)pix * 640 + brOff + oc] = (_Float16)fmaxf(acc[nn][r] * inv + bs, 0.f);
    }
  }
}

// ---------- q/k: 1x1 conv 640->128 + bias -> [b][pix][128] fp16 ----------
__global__ __launch_bounds__(256) void k_qk(const _Float16* __restrict__ featT, const _Float16* __restrict__ wh,
                                            const float* __restrict__ bias, _Float16* __restrict__ oT) {
  int b = blockIdx.y, p0 = blockIdx.x * 64;
  int tid = threadIdx.x, wid = tid >> 6, lane = tid & 63;
  const _Float16* A = featT + (size_t)b * N_PIX * 640;
  int pr = p0 + wid * 16;
  f32x4 acc[8] = {};
  for (int kk = 0; kk < 20; ++kk) {
    f16x8 af = ldnt(A, pr, 640, kk * 32, lane);
#pragma unroll
    for (int nn = 0; nn < 8; ++nn) {
      f16x8 bf = ldnt(wh, nn * 16, 640, kk * 32, lane);
      acc[nn] = mfma16(af, bf, acc[nn]);
    }
  }
  _Float16* O = oT + (size_t)b * N_PIX * 128;
#pragma unroll
  for (int nn = 0; nn < 8; ++nn) {
    int oc = nn * 16 + (lane & 15);
    float bb = bias[oc];
#pragma unroll
    for (int r = 0; r < 4; ++r) {
      int pix = pr + ((lane >> 4) << 2) + r;
      O[(size_t)pix * 128 + oc] = (_Float16)(acc[nn][r] + bb);
    }
  }
}

// ---------- v: 1x1 conv 512->512 + bias -> [b][c][pix] fp16 (channel-major) ----------
__global__ __launch_bounds__(256) void k_v(const _Float16* __restrict__ xT, const _Float16* __restrict__ wvh,
                                           const float* __restrict__ bv, _Float16* __restrict__ vv) {
  int b = blockIdx.z, oc0 = blockIdx.x * 64, p0 = blockIdx.y * 128;
  int tid = threadIdx.x, wid = tid >> 6, lane = tid & 63;
  const _Float16* Bm = xT + (size_t)b * N_PIX * C_IN;
  int or0 = oc0 + wid * 16;
  f32x4 acc[8] = {};
  for (int kk = 0; kk < 16; ++kk) {
    f16x8 af = ldnt(wvh, or0, C_IN, kk * 32, lane);
#pragma unroll
    for (int nn = 0; nn < 8; ++nn) {
      f16x8 bf = ldnt(Bm, p0 + nn * 16, C_IN, kk * 32, lane);
      acc[nn] = mfma16(af, bf, acc[nn]);
    }
  }
  _Float16* V = vv + (size_t)b * C_IN * N_PIX;
#pragma unroll
  for (int r = 0; r < 4; ++r) {
    int oc = or0 + ((lane >> 4) << 2) + r;
    float bb = bv[oc];
#pragma unroll
    for (int nn = 0; nn < 8; ++nn) {
      int pix = p0 + nn * 16 + (lane & 15);
      V[(size_t)oc * N_PIX + pix] = (_Float16)(acc[nn][r] + bb);
    }
  }
}

// ---------- pass 1: partial row max + sumexp over an m-quarter (S^T orientation) ----------
__global__ __launch_bounds__(256) void k_pass1(const _Float16* __restrict__ qT, const _Float16* __restrict__ kT,
                                               float* __restrict__ pmaxP, float* __restrict__ psumP) {
  int b = blockIdx.z, n0 = blockIdx.x * 64, mq = blockIdx.y;
  int tid = threadIdx.x, wid = tid >> 6, lane = tid & 63;
  const _Float16* Q = qT + (size_t)b * N_PIX * 128;
  const _Float16* K = kT + (size_t)b * N_PIX * 128;
  f16x8 qf[4];
#pragma unroll
  for (int kk = 0; kk < 4; ++kk) qf[kk] = ldnt(Q, n0 + wid * 16, 128, kk * 32, lane);
  float mx = -3.4e38f, sm = 0.f;
  for (int it = 0; it < 16; ++it) {
    int m0 = mq * 1024 + it * 64;
#pragma unroll
    for (int mm = 0; mm < 4; ++mm) {
      f32x4 s = {};
#pragma unroll
      for (int kk = 0; kk < 4; ++kk) {
        f16x8 kf = ldnt(K, m0 + mm * 16, 128, kk * 32, lane);
        s = mfma16(kf, qf[kk], s);  // S^T: col = n (lane&15), rows = m
      }
      float vmax = fmaxf(fmaxf(s[0], s[1]), fmaxf(s[2], s[3]));
      float newm = fmaxf(mx, vmax);
      sm = sm * __expf(mx - newm) + __expf(s[0] - newm) + __expf(s[1] - newm) +
           __expf(s[2] - newm) + __expf(s[3] - newm);
      mx = newm;
    }
  }
  // combine lanes holding the same n (lane, lane^16, lane^32)
#pragma unroll
  for (int off = 16; off < 64; off <<= 1) {
    float mo = __shfl_xor(mx, off);
    float lo = __shfl_xor(sm, off);
    float mn = fmaxf(mx, mo);
    sm = sm * __expf(mx - mn) + lo * __expf(mo - mn);
    mx = mn;
  }
  if (lane < 16) {
    size_t idx = ((size_t)(b * 4 + mq)) * N_PIX + n0 + wid * 16 + lane;
    pmaxP[idx] = mx;
    psumP[idx] = sm;
  }
}

// ---------- combine 4 m-quarter partials -> rmax, rsum ----------
__global__ __launch_bounds__(256) void k_comb(const float* __restrict__ pmaxP, const float* __restrict__ psumP,
                                              float* __restrict__ rmax, float* __restrict__ rsum) {
  int i = blockIdx.x * 256 + threadIdx.x;  // 4*4096
  int b = i >> 12, n = i & 4095;
  float m = -3.4e38f, l = 0.f;
#pragma unroll
  for (int q = 0; q < 4; ++q) {
    size_t idx = ((size_t)(b * 4 + q)) * N_PIX + n;
    float mq = pmaxP[idx], lq = psumP[idx];
    float nm = fmaxf(m, mq);
    l = l * __expf(m - nm) + lq * __expf(mq - nm);
    m = nm;
  }
  rmax[(size_t)b * N_PIX + n] = m;
  rsum[(size_t)b * N_PIX + n] = l;
}

// ---------- pass 2: fused S^T recompute -> P -> PV -> y = x + gamma*O/sum ----------
// c-split 2, double-buffered P, one barrier per m-tile.
__global__ __launch_bounds__(256) void k_pass2(const _Float16* __restrict__ qT, const _Float16* __restrict__ kT,
                                               const _Float16* __restrict__ vv, const float* __restrict__ rmax,
                                               const float* __restrict__ rsum, const float* __restrict__ x,
                                               const float* __restrict__ gamma, float* __restrict__ out) {
  __shared__ _Float16 Pb[2][64][72];  // [buf][n][m], stride 72 halves (144B rows: 16B-aligned, 2-way banks)
  int b = blockIdx.z, n0 = blockIdx.x * 64, c0 = blockIdx.y * 256;
  int tid = threadIdx.x, wid = tid >> 6, lane = tid & 63;
  const _Float16* Q = qT + (size_t)b * N_PIX * 128;
  const _Float16* K = kT + (size_t)b * N_PIX * 128;
  const _Float16* V = vv + (size_t)b * C_IN * N_PIX;
  float g = gamma[0];
  f16x8 qf[4];
#pragma unroll
  for (int kk = 0; kk < 4; ++kk) qf[kk] = ldnt(Q, n0 + wid * 16, 128, kk * 32, lane);
  float pmax = rmax[(size_t)b * N_PIX + n0 + wid * 16 + (lane & 15)];  // per-lane n
  f32x4 acc[4][4] = {};

  auto phaseA = [&](int it, int buf) {
    int m0 = it * 64;
#pragma unroll
    for (int mm = 0; mm < 4; ++mm) {
      f32x4 s = {};
#pragma unroll
      for (int kk = 0; kk < 4; ++kk) {
        f16x8 kf = ldnt(K, m0 + mm * 16, 128, kk * 32, lane);
        s = mfma16(kf, qf[kk], s);  // S^T: col=n, row=m -> lane's 4 values contiguous in m
      }
      f16x4 pv;
#pragma unroll
      for (int r = 0; r < 4; ++r) pv[r] = (_Float16)__expf(s[r] - pmax);
      *(f16x4*)(&Pb[buf][wid * 16 + (lane & 15)][mm * 16 + ((lane >> 4) << 2)]) = pv;
    }
  };
  auto phaseB = [&](int it, int buf) {
    int m0 = it * 64;
#pragma unroll
    for (int k2 = 0; k2 < 2; ++k2) {
      f16x8 pb[4];
#pragma unroll
      for (int nn = 0; nn < 4; ++nn)
        pb[nn] = *(const f16x8*)(&Pb[buf][nn * 16 + (lane & 15)][k2 * 32 + ((lane >> 4) << 3)]);
#pragma unroll
      for (int cc = 0; cc < 4; ++cc) {
        f16x8 af = ldnt(V, c0 + wid * 64 + cc * 16, N_PIX, m0 + k2 * 32, lane);
#pragma unroll
        for (int nn = 0; nn < 4; ++nn) acc[cc][nn] = mfma16(af, pb[nn], acc[cc][nn]);
      }
    }
  };

  phaseA(0, 0);
  __syncthreads();
  for (int it = 0; it < 63; ++it) {
    phaseA(it + 1, (it + 1) & 1);  // write other buffer
    phaseB(it, it & 1);            // consume current buffer
    __syncthreads();
  }
  phaseB(63, 1);

  // epilogue: normalize by row sum, y = x + g*O
  float inv_s[4];
#pragma unroll
  for (int nn = 0; nn < 4; ++nn) {
    int pix = n0 + nn * 16 + (lane & 15);
    inv_s[nn] = 1.f / rsum[(size_t)b * N_PIX + pix];
  }
#pragma unroll
  for (int cc = 0; cc < 4; ++cc) {
#pragma unroll
    for (int r = 0; r < 4; ++r) {
      int oc = c0 + wid * 64 + cc * 16 + ((lane >> 4) << 2) + r;
#pragma unroll
      for (int nn = 0; nn < 4; ++nn) {
        int pix = n0 + nn * 16 + (lane & 15);
        size_t idx = ((size_t)(b * C_IN + oc)) * N_PIX + pix;
        out[idx] = fmaf(g * inv_s[nn], acc[cc][nn][r], x[idx]);
      }
    }
  }
}

extern "C" void kernel_launch(void* const* d_in, const int* in_sizes, int n_in,
                              void* d_out, int out_size, void* d_ws, size_t ws_size,
                              hipStream_t stream) {
  const float* x = (const float*)d_in[0];
  const float* wa1 = (const float*)d_in[1];
  const float* wa2 = (const float*)d_in[2];
  const float* wa3 = (const float*)d_in[3];
  const float* wa4 = (const float*)d_in[4];
  const float* wa5 = (const float*)d_in[5];
  const float* bnS = (const float*)d_in[6];
  const float* bnB = (const float*)d_in[7];
  const float* wq = (const float*)d_in[8];
  const float* bq = (const float*)d_in[9];
  const float* wk = (const float*)d_in[10];
  const float* bk = (const float*)d_in[11];
  const float* wv = (const float*)d_in[12];
  const float* bv = (const float*)d_in[13];
  const float* gamma = (const float*)d_in[14];

  char* ws = (char*)d_ws;
  size_t off = 0;
  auto alloc = [&](size_t bytes) -> char* {
    char* p = ws + off;
    off = (off + bytes + 255) & ~(size_t)255;
    return p;
  };
  _Float16* xT = (_Float16*)alloc((size_t)4 * 4096 * 512 * 2);
  _Float16* featT = (_Float16*)alloc((size_t)4 * 4096 * 640 * 2);
  _Float16* qT = (_Float16*)alloc((size_t)4 * 4096 * 128 * 2);
  _Float16* kT = (_Float16*)alloc((size_t)4 * 4096 * 128 * 2);
  _Float16* vvp = (_Float16*)alloc((size_t)4 * 512 * 4096 * 2);
  _Float16* w1h = (_Float16*)alloc((size_t)128 * 512 * 2);
  _Float16* wph = (_Float16*)alloc((size_t)3 * 9 * 128 * 512 * 2);
  _Float16* wqh = (_Float16*)alloc((size_t)128 * 640 * 2);
  _Float16* wkh = (_Float16*)alloc((size_t)128 * 640 * 2);
  _Float16* wvh = (_Float16*)alloc((size_t)512 * 512 * 2);
  float* meanv = (float*)alloc((size_t)4 * 512 * 4);
  _Float16* p5h = (_Float16*)alloc((size_t)4 * 128 * 2);
  float* rmax = (float*)alloc((size_t)4 * 4096 * 4);
  float* rsum = (float*)alloc((size_t)4 * 4096 * 4);
  float* pmaxP = (float*)alloc((size_t)4 * 4 * 4096 * 4);
  float* psumP = (float*)alloc((size_t)4 * 4 * 4096 * 4);
  if (off > ws_size) return;  // workspace too small -> fail loudly via wrong output

  float* out = (float*)d_out;

  // stage inputs
  hipLaunchKernelGGL(k_xT, dim3(128, 16, 4), dim3(256), 0, stream, x, xT);
  hipLaunchKernelGGL(k_f2h, dim3(256), dim3(256), 0, stream, wa1, w1h, 65536);
  hipLaunchKernelGGL(k_f2h, dim3(320), dim3(256), 0, stream, wq, wqh, 81920);
  hipLaunchKernelGGL(k_f2h, dim3(320), dim3(256), 0, stream, wk, wkh, 81920);
  hipLaunchKernelGGL(k_f2h, dim3(1024), dim3(256), 0, stream, wv, wvh, 262144);
  hipLaunchKernelGGL(k_packw, dim3(6912), dim3(256), 0, stream, wa2, wa3, wa4, wph);
  // ASPP
  hipLaunchKernelGGL(k_mean, dim3(512, 4), dim3(256), 0, stream, x, meanv);
  hipLaunchKernelGGL(k_p5, dim3(4), dim3(128), 0, stream, wa5, meanv, bnS + 4 * 128, bnB + 4 * 128, p5h);
  hipLaunchKernelGGL(k_b5, dim3(8192), dim3(256), 0, stream, p5h, featT);
  hipLaunchKernelGGL(k_conv1, dim3(64, 4), dim3(256), 0, stream, xT, w1h, bnS, bnB, featT);
  hipLaunchKernelGGL(k_conv3, dim3(64, 2, 4), dim3(256), 0, stream, xT, wph + (size_t)0 * 9 * 128 * 512, 2,
                     bnS + 128, bnB + 128, featT, 128);
  hipLaunchKernelGGL(k_conv3, dim3(64, 2, 4), dim3(256), 0, stream, xT, wph + (size_t)1 * 9 * 128 * 512, 3,
                     bnS + 256, bnB + 256, featT, 256);
  hipLaunchKernelGGL(k_conv3, dim3(64, 2, 4), dim3(256), 0, stream, xT, wph + (size_t)2 * 9 * 128 * 512, 6,
                     bnS + 384, bnB + 384, featT, 384);
  // q, k, v
  hipLaunchKernelGGL(k_qk, dim3(64, 4), dim3(256), 0, stream, featT, wqh, bq, qT);
  hipLaunchKernelGGL(k_qk, dim3(64, 4), dim3(256), 0, stream, featT, wkh, bk, kT);
  hipLaunchKernelGGL(k_v, dim3(8, 32, 4), dim3(256), 0, stream, xT, wvh, bv, vvp);
  // attention
  hipLaunchKernelGGL(k_pass1, dim3(64, 4, 4), dim3(256), 0, stream, qT, kT, pmaxP, psumP);
  hipLaunchKernelGGL(k_comb, dim3(64), dim3(256), 0, stream, pmaxP, psumP, rmax, rsum);
  hipLaunchKernelGGL(k_pass2, dim3(64, 2, 4), dim3(256), 0, stream, qT, kT, vvp, rmax, rsum, x, gamma, out);
}